// Round 1
// baseline (627.796 us; speedup 1.0000x reference)
//
#include <hip/hip_runtime.h>

typedef _Float16 half8 __attribute__((ext_vector_type(8)));
typedef float floatx4 __attribute__((ext_vector_type(4)));

#define LBF 2304   // Lb == Lf
#define K1  1152

__device__ __forceinline__ int Pswap(int x) { return (x % 48) * 48 + x / 48; }

// ---------------- prep: fp patches (foreground, downsampled, 3x3, pad 1) ------
__global__ void prep_fp(const float* __restrict__ f, _Float16* __restrict__ fp) {
    int k = blockIdx.x * 128 + threadIdx.x;   // [0,1152)
    int p = blockIdx.y;                       // [0,2304)
    int b = blockIdx.z;
    int c = k / 9, r = k % 9, u = r / 3, v = r % 3;
    int pi = p / 48, pj = p % 48;
    int y = pi - 1 + u, x = pj - 1 + v;
    float val = 0.f;
    if ((unsigned)y < 48u && (unsigned)x < 48u)
        val = f[(((long)b * 128 + c) * 96 + 2 * y) * 96 + 2 * x];
    fp[((long)b * LBF + p) * K1 + k] = (_Float16)val;
}

// ---------------- prep: wn normalized background patches ----------------------
__global__ void prep_wn(const float* __restrict__ bsrc, _Float16* __restrict__ wn) {
    int p = blockIdx.x, b = blockIdx.y;
    int tid = threadIdx.x;  // 128 threads, 9 elems each
    int pi = p / 48, pj = p % 48;
    float w[9];
    float ss = 0.f;
#pragma unroll
    for (int t = 0; t < 9; t++) {
        int k = tid + t * 128;
        int c = k / 9, r = k % 9, u = r / 3, v = r % 3;
        int y = pi - 1 + u, x = pj - 1 + v;
        float val = 0.f;
        if ((unsigned)y < 48u && (unsigned)x < 48u)
            val = bsrc[(((long)b * 128 + c) * 96 + 2 * y) * 96 + 2 * x];
        w[t] = val;
        ss += val * val;
    }
    for (int m = 32; m; m >>= 1) ss += __shfl_xor(ss, m);
    __shared__ float sh[2];
    if ((tid & 63) == 0) sh[tid >> 6] = ss;
    __syncthreads();
    float denom = sqrtf(sh[0] + sh[1] + 0.1152f);  // sum(w^2 + ESC), ESC*1152
    float inv = 1.f / denom;
#pragma unroll
    for (int t = 0; t < 9; t++) {
        int k = tid + t * 128;
        wn[((long)b * LBF + p) * K1 + k] = (_Float16)(w[t] * inv);
    }
}

// ---------------- prep: Wt[n=(c,u,v)][p] = raw_w patches (4x4 stride 2 pad 1) --
__global__ void prep_wt(const float* __restrict__ bsrc, _Float16* __restrict__ wt) {
    int p = blockIdx.x * 256 + threadIdx.x;   // [0,2304)
    int n = blockIdx.y;                       // [0,2048)
    int b = blockIdx.z;
    int c = n >> 4, u = (n >> 2) & 3, v = n & 3;
    int pi = p / 48, pj = p % 48;
    int y = 2 * pi - 1 + u, x = 2 * pj - 1 + v;
    float val = 0.f;
    if ((unsigned)y < 96u && (unsigned)x < 96u)
        val = bsrc[(((long)b * 128 + c) * 96 + y) * 96 + x];
    wt[((long)b * 2048 + n) * LBF + p] = (_Float16)val;
}

// ---------------- prep: mm flags from mask ------------------------------------
__global__ void prep_mm(const float* __restrict__ mask, float* __restrict__ mm) {
    int p = blockIdx.x * 256 + threadIdx.x;
    if (p >= LBF) return;
    int pi = p / 48, pj = p % 48;
    float s = 0.f;
#pragma unroll
    for (int u = 0; u < 3; u++)
#pragma unroll
        for (int v = 0; v < 3; v++) {
            int y = pi - 1 + u, x = pj - 1 + v;
            if ((unsigned)y < 48u && (unsigned)x < 48u)
                s += mask[(8 * y) * 384 + 8 * x];
        }
    mm[p] = (s == 0.f) ? 1.f : 0.f;
}

// ---------------- NT GEMM: C[M,N] = A[M,K] * B[N,K]^T, fp16 in / f32 out ------
__global__ __launch_bounds__(256)
void gemm_nt(const _Float16* __restrict__ A, const _Float16* __restrict__ B,
             float* __restrict__ C, int M, int N, int K,
             long sA, long sB, long sC) {
    A += blockIdx.z * sA; B += blockIdx.z * sB; C += blockIdx.z * sC;
    const int tid = threadIdx.x;
    const int lane = tid & 63, wave = tid >> 6;
    const int wr = wave >> 1, wc = wave & 1;
    const int m0 = blockIdx.y * 128, n0 = blockIdx.x * 128;

    __shared__ _Float16 lA[128][40];   // stride 40 -> 2-way LDS aliasing (free)
    __shared__ _Float16 lB[128][40];

    floatx4 acc[4][4] = {};

    const int lm = lane & 15, q = lane >> 4;
    const int r0 = tid >> 2, cc0 = (tid & 3) * 8;

    for (int k0 = 0; k0 < K; k0 += 32) {
        uint4 a0 = *(const uint4*)(A + (long)(m0 + r0) * K + k0 + cc0);
        uint4 a1 = *(const uint4*)(A + (long)(m0 + r0 + 64) * K + k0 + cc0);
        uint4 b0 = *(const uint4*)(B + (long)(n0 + r0) * K + k0 + cc0);
        uint4 b1 = *(const uint4*)(B + (long)(n0 + r0 + 64) * K + k0 + cc0);
        __syncthreads();
        *(uint4*)&lA[r0][cc0] = a0;
        *(uint4*)&lA[r0 + 64][cc0] = a1;
        *(uint4*)&lB[r0][cc0] = b0;
        *(uint4*)&lB[r0 + 64][cc0] = b1;
        __syncthreads();
        half8 af[4], bf[4];
#pragma unroll
        for (int t = 0; t < 4; t++) {
            af[t] = *(const half8*)&lA[wr * 64 + t * 16 + lm][q * 8];
            bf[t] = *(const half8*)&lB[wc * 64 + t * 16 + lm][q * 8];
        }
#pragma unroll
        for (int i = 0; i < 4; i++)
#pragma unroll
            for (int j = 0; j < 4; j++)
                acc[i][j] = __builtin_amdgcn_mfma_f32_16x16x32_f16(af[i], bf[j], acc[i][j], 0, 0, 0);
    }
    // C/D layout: col = lane&15, row = (lane>>4)*4 + reg   [m89-verified]
    const int col = n0 + wc * 64 + lm;
    const int rowq = q * 4;
#pragma unroll
    for (int i = 0; i < 4; i++) {
        int row = m0 + wr * 64 + i * 16 + rowq;
#pragma unroll
        for (int j = 0; j < 4; j++)
#pragma unroll
            for (int r = 0; r < 4; r++)
                C[(long)(row + r) * N + col + j * 16] = acc[i][j][r];
    }
}

// ---------------- fuse: 9-tap double-diagonal stencil on S^T ------------------
// final[i,j] = sum_{d2,d1} S[P(P(i)+d2)+d1, P(P(j)+d2)+d1] with per-pass bounds;
// stored transposed: FT[j,i], ST[j,i].
__global__ void fuse9(const float* __restrict__ ST, float* __restrict__ FT) {
    int i = blockIdx.x * 64 + (threadIdx.x & 63);   // background (col)
    int j = blockIdx.y * 4 + (threadIdx.x >> 6);    // foreground (row)
    long boff = (long)blockIdx.z * LBF * LBF;
    const float* S = ST + boff;
    float acc = 0.f;
    int Pi = Pswap(i), Pj = Pswap(j);
#pragma unroll
    for (int d2 = -1; d2 <= 1; d2++) {
        int i2 = Pi + d2, j2 = Pj + d2;
        if ((unsigned)i2 >= 2304u || (unsigned)j2 >= 2304u) continue;
        int ci = Pswap(i2), rj = Pswap(j2);
#pragma unroll
        for (int d1 = -1; d1 <= 1; d1++) {
            int cc = ci + d1, rr = rj + d1;
            if ((unsigned)cc >= 2304u || (unsigned)rr >= 2304u) continue;
            acc += S[(long)rr * LBF + cc];
        }
    }
    FT[boff + (long)j * LBF + i] = acc;
}

// ---------------- softmax over background axis, masked, -> fp16 attT ----------
__global__ __launch_bounds__(256)
void softmax_att(const float* __restrict__ FT, const float* __restrict__ mmv,
                 _Float16* __restrict__ attT) {
    int j = blockIdx.x, b = blockIdx.y;
    const float* row = FT + ((long)b * LBF + j) * LBF;
    _Float16* out = attT + ((long)b * LBF + j) * LBF;
    int tid = threadIdx.x;
    float v[9], msk[9];
    float mx = -1e30f;
#pragma unroll
    for (int t = 0; t < 9; t++) {
        int i = tid + t * 256;
        float mi = mmv[i];
        float x = row[i] * mi * 10.f;   // scores * mm * SCALE (masked -> 0)
        v[t] = x; msk[t] = mi;
        mx = fmaxf(mx, x);
    }
    for (int m = 32; m; m >>= 1) mx = fmaxf(mx, __shfl_xor(mx, m));
    __shared__ float sh[4], sh2[4];
    if ((tid & 63) == 0) sh[tid >> 6] = mx;
    __syncthreads();
    mx = fmaxf(fmaxf(sh[0], sh[1]), fmaxf(sh[2], sh[3]));
    float sum = 0.f;
#pragma unroll
    for (int t = 0; t < 9; t++) { v[t] = __expf(v[t] - mx); sum += v[t]; }
    for (int m = 32; m; m >>= 1) sum += __shfl_xor(sum, m);
    if ((tid & 63) == 0) sh2[tid >> 6] = sum;
    __syncthreads();
    sum = sh2[0] + sh2[1] + sh2[2] + sh2[3];
    float inv = 1.f / sum;
#pragma unroll
    for (int t = 0; t < 9; t++)
        out[tid + t * 256] = (_Float16)(v[t] * inv * msk[t]);
}

// ---------------- scatter: transposed-conv gather, /4 -------------------------
__global__ void scatter_out(const float* __restrict__ Mb_, float* __restrict__ out) {
    int yx = blockIdx.x * 256 + threadIdx.x;  // [0, 9216)
    int c = blockIdx.y, b = blockIdx.z;
    int y = yx / 96, x = yx % 96;
    const float* Mb = Mb_ + (long)b * LBF * 2048;
    float s = 0.f;
    for (int uu = (y + 1) & 1; uu < 4; uu += 2) {
        int fi = (y + 1 - uu) >> 1;
        if ((unsigned)fi >= 48u) continue;
        for (int vv = (x + 1) & 1; vv < 4; vv += 2) {
            int fj = (x + 1 - vv) >> 1;
            if ((unsigned)fj >= 48u) continue;
            s += Mb[(long)(fi * 48 + fj) * 2048 + c * 16 + uu * 4 + vv];
        }
    }
    out[(((long)b * 128 + c) * 96 + y) * 96 + x] = 0.25f * s;
}

extern "C" void kernel_launch(void* const* d_in, const int* in_sizes, int n_in,
                              void* d_out, int out_size, void* d_ws, size_t ws_size,
                              hipStream_t stream) {
    const float* f    = (const float*)d_in[0];
    const float* bsrc = (const float*)d_in[1];
    const float* mask = (const float*)d_in[2];
    float* out = (float*)d_out;

    // workspace layout (region reuse; peak ~208 MB):
    //  bufA [0, 85MB):      fp+wn  -> FT -> M
    //  bufB [85MB, 170MB):  ST -> attT
    //  Wt   [170MB, 206MB)
    //  mm   tail
    char* ws = (char*)d_ws;
    const size_t offWn  = 21233664;      // 2304*1152*2
    const size_t offB   = 84934656;      // bufA size = 4*2304*2304*4 / ... 85MB
    const size_t offWt  = 169869312;
    const size_t offMm  = 207618048;
    const size_t NEED   = 207627264;
    if (ws_size < NEED) return;  // visible failure, no OOB writes

    _Float16* fp   = (_Float16*)(ws + 0);
    _Float16* wn   = (_Float16*)(ws + offWn);
    float*    ST   = (float*)(ws + offB);
    float*    FT   = (float*)(ws + 0);
    _Float16* attT = (_Float16*)(ws + offB);
    float*    Mout = (float*)(ws + 0);
    _Float16* Wt   = (_Float16*)(ws + offWt);
    float*    mmv  = (float*)(ws + offMm);

    prep_mm<<<dim3(9), 256, 0, stream>>>(mask, mmv);
    prep_fp<<<dim3(9, 2304, 4), 128, 0, stream>>>(f, fp);
    prep_wn<<<dim3(2304, 4), 128, 0, stream>>>(bsrc, wn);
    prep_wt<<<dim3(9, 2048, 4), 256, 0, stream>>>(bsrc, Wt);

    // GEMM1: ST[j,i] = sum_k fp[j,k] * wn[i,k]   (Lf x Lb, f32)
    gemm_nt<<<dim3(18, 18, 4), 256, 0, stream>>>(fp, wn, ST, 2304, 2304, 1152,
        (long)2304 * 1152, (long)2304 * 1152, (long)2304 * 2304);

    fuse9<<<dim3(36, 576, 4), 256, 0, stream>>>(ST, FT);
    softmax_att<<<dim3(2304, 4), 256, 0, stream>>>(FT, mmv, attT);

    // GEMM2: M[j,n] = sum_i attT[j,i] * Wt[n,i]   (Lf x 2048, f32)
    gemm_nt<<<dim3(16, 18, 4), 256, 0, stream>>>(attT, Wt, Mout, 2304, 2048, 2304,
        (long)2304 * 2304, (long)2048 * 2304, (long)2304 * 2048);

    scatter_out<<<dim3(36, 128, 4), 256, 0, stream>>>(Mout, out);
}

// Round 2
// 613.065 us; speedup vs baseline: 1.0240x; 1.0240x over previous
//
#include <hip/hip_runtime.h>

typedef _Float16 half8 __attribute__((ext_vector_type(8)));
typedef float floatx4 __attribute__((ext_vector_type(4)));

#define LBF 2304   // Lb == Lf
#define K1  1152

__device__ __forceinline__ int Pswap(int x) { return (x % 48) * 48 + x / 48; }

__device__ __forceinline__ void gll16(const _Float16* g, _Float16* l) {
    __builtin_amdgcn_global_load_lds((const __attribute__((address_space(1))) void*)g,
                                     (__attribute__((address_space(3))) void*)l, 16, 0, 0);
}

// ---------------- prep: fp patches (foreground, downsampled, 3x3, pad 1) ------
__global__ void prep_fp(const float* __restrict__ f, _Float16* __restrict__ fp) {
    int k = blockIdx.x * 128 + threadIdx.x;   // [0,1152)
    int p = blockIdx.y;                       // [0,2304)
    int b = blockIdx.z;
    int c = k / 9, r = k % 9, u = r / 3, v = r % 3;
    int pi = p / 48, pj = p % 48;
    int y = pi - 1 + u, x = pj - 1 + v;
    float val = 0.f;
    if ((unsigned)y < 48u && (unsigned)x < 48u)
        val = f[(((long)b * 128 + c) * 96 + 2 * y) * 96 + 2 * x];
    fp[((long)b * LBF + p) * K1 + k] = (_Float16)val;
}

// ---------------- prep: wn normalized background patches ----------------------
__global__ void prep_wn(const float* __restrict__ bsrc, _Float16* __restrict__ wn) {
    int p = blockIdx.x, b = blockIdx.y;
    int tid = threadIdx.x;  // 128 threads, 9 elems each
    int pi = p / 48, pj = p % 48;
    float w[9];
    float ss = 0.f;
#pragma unroll
    for (int t = 0; t < 9; t++) {
        int k = tid + t * 128;
        int c = k / 9, r = k % 9, u = r / 3, v = r % 3;
        int y = pi - 1 + u, x = pj - 1 + v;
        float val = 0.f;
        if ((unsigned)y < 48u && (unsigned)x < 48u)
            val = bsrc[(((long)b * 128 + c) * 96 + 2 * y) * 96 + 2 * x];
        w[t] = val;
        ss += val * val;
    }
    for (int m = 32; m; m >>= 1) ss += __shfl_xor(ss, m);
    __shared__ float sh[2];
    if ((tid & 63) == 0) sh[tid >> 6] = ss;
    __syncthreads();
    float denom = sqrtf(sh[0] + sh[1] + 0.1152f);  // sum(w^2 + ESC), ESC*1152
    float inv = 1.f / denom;
#pragma unroll
    for (int t = 0; t < 9; t++) {
        int k = tid + t * 128;
        wn[((long)b * LBF + p) * K1 + k] = (_Float16)(w[t] * inv);
    }
}

// ---------------- prep: Wt[n=(c,u,v)][p] = raw_w patches (4x4 stride 2 pad 1) --
__global__ void prep_wt(const float* __restrict__ bsrc, _Float16* __restrict__ wt) {
    int p = blockIdx.x * 256 + threadIdx.x;   // [0,2304)
    int n = blockIdx.y;                       // [0,2048)
    int b = blockIdx.z;
    int c = n >> 4, u = (n >> 2) & 3, v = n & 3;
    int pi = p / 48, pj = p % 48;
    int y = 2 * pi - 1 + u, x = 2 * pj - 1 + v;
    float val = 0.f;
    if ((unsigned)y < 96u && (unsigned)x < 96u)
        val = bsrc[(((long)b * 128 + c) * 96 + y) * 96 + x];
    wt[((long)b * 2048 + n) * LBF + p] = (_Float16)val;
}

// ---------------- prep: mm flags from mask ------------------------------------
__global__ void prep_mm(const float* __restrict__ mask, float* __restrict__ mm) {
    int p = blockIdx.x * 256 + threadIdx.x;
    if (p >= LBF) return;
    int pi = p / 48, pj = p % 48;
    float s = 0.f;
#pragma unroll
    for (int u = 0; u < 3; u++)
#pragma unroll
        for (int v = 0; v < 3; v++) {
            int y = pi - 1 + u, x = pj - 1 + v;
            if ((unsigned)y < 48u && (unsigned)x < 48u)
                s += mask[(8 * y) * 384 + 8 * x];
        }
    mm[p] = (s == 0.f) ? 1.f : 0.f;
}

// ---------------- NT GEMM: C[M,N] = A[M,K] * B[N,K]^T, fp16 in / f32 out ------
// global_load_lds(16B) staging; XOR-swizzled chunk placement so ds_read_b128
// fragment reads are bank-conflict-free on the unpadded 64B-row LDS layout.
__global__ __launch_bounds__(256)
void gemm_nt(const _Float16* __restrict__ A, const _Float16* __restrict__ B,
             float* __restrict__ C, int M, int N, int K,
             long sA, long sB, long sC) {
    A += blockIdx.z * sA; B += blockIdx.z * sB; C += blockIdx.z * sC;
    const int tid = threadIdx.x;
    const int lane = tid & 63, wave = tid >> 6;
    const int wr = wave >> 1, wc = wave & 1;
    const int m0 = blockIdx.y * 128, n0 = blockIdx.x * 128;

    __shared__ _Float16 lA[128 * 32];   // 128 rows x 32 halves (64 B/row), no pad
    __shared__ _Float16 lB[128 * 32];

    floatx4 acc[4][4] = {};

    const int lm = lane & 15, q = lane >> 4;
    const int pc = (q ^ ((lm >> 1) & 3)) * 8;   // physical chunk offset (halves)

    // staging: thread t stages physical slot t (16 B) of rounds {0,1};
    // row = r*64 + t/4, phys chunk = t&3, logical chunk = (t&3) ^ ((row>>1)&3)
    const int srow = tid >> 2;                       // 0..63
    const int qg = (((tid & 3) ^ ((srow >> 1) & 3)) * 8);  // same for both rounds
    const _Float16* pa0 = A + (long)(m0 + srow) * K + qg;
    const _Float16* pa1 = A + (long)(m0 + srow + 64) * K + qg;
    const _Float16* pb0 = B + (long)(n0 + srow) * K + qg;
    const _Float16* pb1 = B + (long)(n0 + srow + 64) * K + qg;
    _Float16* ldsA0 = &lA[(wave * 16) * 32];         // wave-uniform bases
    _Float16* ldsA1 = &lA[(64 + wave * 16) * 32];
    _Float16* ldsB0 = &lB[(wave * 16) * 32];
    _Float16* ldsB1 = &lB[(64 + wave * 16) * 32];

    for (int k0 = 0; k0 < K; k0 += 32) {
        __syncthreads();                 // protect LDS from overwrite
        gll16(pa0 + k0, ldsA0);
        gll16(pa1 + k0, ldsA1);
        gll16(pb0 + k0, ldsB0);
        gll16(pb1 + k0, ldsB1);
        __syncthreads();                 // drains vmcnt before reads
        half8 af[4], bf[4];
#pragma unroll
        for (int t = 0; t < 4; t++) {
            af[t] = *(const half8*)&lA[(wr * 64 + t * 16 + lm) * 32 + pc];
            bf[t] = *(const half8*)&lB[(wc * 64 + t * 16 + lm) * 32 + pc];
        }
#pragma unroll
        for (int i = 0; i < 4; i++)
#pragma unroll
            for (int j = 0; j < 4; j++)
                acc[i][j] = __builtin_amdgcn_mfma_f32_16x16x32_f16(af[i], bf[j], acc[i][j], 0, 0, 0);
    }
    // C/D layout: col = lane&15, row = (lane>>4)*4 + reg   [m89-verified]
    const int col = n0 + wc * 64 + lm;
    const int rowq = q * 4;
#pragma unroll
    for (int i = 0; i < 4; i++) {
        int row = m0 + wr * 64 + i * 16 + rowq;
#pragma unroll
        for (int j = 0; j < 4; j++)
#pragma unroll
            for (int r = 0; r < 4; r++)
                C[(long)(row + r) * N + col + j * 16] = acc[i][j][r];
    }
}

// ---------------- fuse: 9-tap double-diagonal stencil on S^T ------------------
__global__ void fuse9(const float* __restrict__ ST, float* __restrict__ FT) {
    int i = blockIdx.x * 64 + (threadIdx.x & 63);   // background (col)
    int j = blockIdx.y * 4 + (threadIdx.x >> 6);    // foreground (row)
    long boff = (long)blockIdx.z * LBF * LBF;
    const float* S = ST + boff;
    float acc = 0.f;
    int Pi = Pswap(i), Pj = Pswap(j);
#pragma unroll
    for (int d2 = -1; d2 <= 1; d2++) {
        int i2 = Pi + d2, j2 = Pj + d2;
        if ((unsigned)i2 >= 2304u || (unsigned)j2 >= 2304u) continue;
        int ci = Pswap(i2), rj = Pswap(j2);
#pragma unroll
        for (int d1 = -1; d1 <= 1; d1++) {
            int cc = ci + d1, rr = rj + d1;
            if ((unsigned)cc >= 2304u || (unsigned)rr >= 2304u) continue;
            acc += S[(long)rr * LBF + cc];
        }
    }
    FT[boff + (long)j * LBF + i] = acc;
}

// ---------------- softmax over background axis, masked, -> fp16 attT ----------
__global__ __launch_bounds__(256)
void softmax_att(const float* __restrict__ FT, const float* __restrict__ mmv,
                 _Float16* __restrict__ attT) {
    int j = blockIdx.x, b = blockIdx.y;
    const float* row = FT + ((long)b * LBF + j) * LBF;
    _Float16* out = attT + ((long)b * LBF + j) * LBF;
    int tid = threadIdx.x;
    float v[9], msk[9];
    float mx = -1e30f;
#pragma unroll
    for (int t = 0; t < 9; t++) {
        int i = tid + t * 256;
        float mi = mmv[i];
        float x = row[i] * mi * 10.f;   // scores * mm * SCALE (masked -> 0)
        v[t] = x; msk[t] = mi;
        mx = fmaxf(mx, x);
    }
    for (int m = 32; m; m >>= 1) mx = fmaxf(mx, __shfl_xor(mx, m));
    __shared__ float sh[4], sh2[4];
    if ((tid & 63) == 0) sh[tid >> 6] = mx;
    __syncthreads();
    mx = fmaxf(fmaxf(sh[0], sh[1]), fmaxf(sh[2], sh[3]));
    float sum = 0.f;
#pragma unroll
    for (int t = 0; t < 9; t++) { v[t] = __expf(v[t] - mx); sum += v[t]; }
    for (int m = 32; m; m >>= 1) sum += __shfl_xor(sum, m);
    if ((tid & 63) == 0) sh2[tid >> 6] = sum;
    __syncthreads();
    sum = sh2[0] + sh2[1] + sh2[2] + sh2[3];
    float inv = 1.f / sum;
#pragma unroll
    for (int t = 0; t < 9; t++)
        out[tid + t * 256] = (_Float16)(v[t] * inv * msk[t]);
}

// ---------------- scatter: transposed-conv gather, /4 -------------------------
__global__ void scatter_out(const float* __restrict__ Mb_, float* __restrict__ out) {
    int yx = blockIdx.x * 256 + threadIdx.x;  // [0, 9216)
    int c = blockIdx.y, b = blockIdx.z;
    int y = yx / 96, x = yx % 96;
    const float* Mb = Mb_ + (long)b * LBF * 2048;
    float s = 0.f;
    for (int uu = (y + 1) & 1; uu < 4; uu += 2) {
        int fi = (y + 1 - uu) >> 1;
        if ((unsigned)fi >= 48u) continue;
        for (int vv = (x + 1) & 1; vv < 4; vv += 2) {
            int fj = (x + 1 - vv) >> 1;
            if ((unsigned)fj >= 48u) continue;
            s += Mb[(long)(fi * 48 + fj) * 2048 + c * 16 + uu * 4 + vv];
        }
    }
    out[(((long)b * 128 + c) * 96 + y) * 96 + x] = 0.25f * s;
}

extern "C" void kernel_launch(void* const* d_in, const int* in_sizes, int n_in,
                              void* d_out, int out_size, void* d_ws, size_t ws_size,
                              hipStream_t stream) {
    const float* f    = (const float*)d_in[0];
    const float* bsrc = (const float*)d_in[1];
    const float* mask = (const float*)d_in[2];
    float* out = (float*)d_out;

    char* ws = (char*)d_ws;
    const size_t offWn  = 21233664;      // 2304*1152*2
    const size_t offB   = 84934656;
    const size_t offWt  = 169869312;
    const size_t offMm  = 207618048;
    const size_t NEED   = 207627264;
    if (ws_size < NEED) return;  // visible failure, no OOB writes

    _Float16* fp   = (_Float16*)(ws + 0);
    _Float16* wn   = (_Float16*)(ws + offWn);
    float*    ST   = (float*)(ws + offB);
    float*    FT   = (float*)(ws + 0);
    _Float16* attT = (_Float16*)(ws + offB);
    float*    Mout = (float*)(ws + 0);
    _Float16* Wt   = (_Float16*)(ws + offWt);
    float*    mmv  = (float*)(ws + offMm);

    prep_mm<<<dim3(9), 256, 0, stream>>>(mask, mmv);
    prep_fp<<<dim3(9, 2304, 4), 128, 0, stream>>>(f, fp);
    prep_wn<<<dim3(2304, 4), 128, 0, stream>>>(bsrc, wn);
    prep_wt<<<dim3(9, 2048, 4), 256, 0, stream>>>(bsrc, Wt);

    // GEMM1: ST[j,i] = sum_k fp[j,k] * wn[i,k]   (Lf x Lb, f32)
    gemm_nt<<<dim3(18, 18, 4), 256, 0, stream>>>(fp, wn, ST, 2304, 2304, 1152,
        (long)2304 * 1152, (long)2304 * 1152, (long)2304 * 2304);

    fuse9<<<dim3(36, 576, 4), 256, 0, stream>>>(ST, FT);
    softmax_att<<<dim3(2304, 4), 256, 0, stream>>>(FT, mmv, attT);

    // GEMM2: M[j,n] = sum_i attT[j,i] * Wt[n,i]   (Lf x 2048, f32)
    gemm_nt<<<dim3(16, 18, 4), 256, 0, stream>>>(attT, Wt, Mout, 2304, 2048, 2304,
        (long)2304 * 2304, (long)2048 * 2304, (long)2304 * 2048);

    scatter_out<<<dim3(36, 128, 4), 256, 0, stream>>>(Mout, out);
}

// Round 3
// 581.009 us; speedup vs baseline: 1.0805x; 1.0552x over previous
//
#include <hip/hip_runtime.h>

typedef _Float16 half8 __attribute__((ext_vector_type(8)));
typedef float floatx4 __attribute__((ext_vector_type(4)));

#define LBF 2304   // Lb == Lf
#define K1  1152
#define LDK2 2304  // worst-case compacted stride (Kc can be up to 2304)

__device__ __forceinline__ int Pswap(int x) { return (x % 48) * 48 + x / 48; }

__device__ __forceinline__ void gll16(const _Float16* g, _Float16* l) {
    __builtin_amdgcn_global_load_lds((const __attribute__((address_space(1))) void*)g,
                                     (__attribute__((address_space(3))) void*)l, 16, 0, 0);
}

// ---------------- prep: fp patches (foreground, downsampled, 3x3, pad 1) ------
__global__ void prep_fp(const float* __restrict__ f, _Float16* __restrict__ fp) {
    int k = blockIdx.x * 128 + threadIdx.x;   // [0,1152)
    int p = blockIdx.y;                       // [0,2304)
    int b = blockIdx.z;
    int c = k / 9, r = k % 9, u = r / 3, v = r % 3;
    int pi = p / 48, pj = p % 48;
    int y = pi - 1 + u, x = pj - 1 + v;
    float val = 0.f;
    if ((unsigned)y < 48u && (unsigned)x < 48u)
        val = f[(((long)b * 128 + c) * 96 + 2 * y) * 96 + 2 * x];
    fp[((long)b * LBF + p) * K1 + k] = (_Float16)val;
}

// ---------------- prep: wn normalized background patches ----------------------
__global__ void prep_wn(const float* __restrict__ bsrc, _Float16* __restrict__ wn) {
    int p = blockIdx.x, b = blockIdx.y;
    int tid = threadIdx.x;  // 128 threads, 9 elems each
    int pi = p / 48, pj = p % 48;
    float w[9];
    float ss = 0.f;
#pragma unroll
    for (int t = 0; t < 9; t++) {
        int k = tid + t * 128;
        int c = k / 9, r = k % 9, u = r / 3, v = r % 3;
        int y = pi - 1 + u, x = pj - 1 + v;
        float val = 0.f;
        if ((unsigned)y < 48u && (unsigned)x < 48u)
            val = bsrc[(((long)b * 128 + c) * 96 + 2 * y) * 96 + 2 * x];
        w[t] = val;
        ss += val * val;
    }
    for (int m = 32; m; m >>= 1) ss += __shfl_xor(ss, m);
    __shared__ float sh[2];
    if ((tid & 63) == 0) sh[tid >> 6] = ss;
    __syncthreads();
    float denom = sqrtf(sh[0] + sh[1] + 0.1152f);  // sum(w^2 + ESC)
    float inv = 1.f / denom;
#pragma unroll
    for (int t = 0; t < 9; t++) {
        int k = tid + t * 128;
        wn[((long)b * LBF + p) * K1 + k] = (_Float16)(w[t] * inv);
    }
}

// ---------------- prep: mm flags from mask ------------------------------------
__global__ void prep_mm(const float* __restrict__ mask, float* __restrict__ mm) {
    int p = blockIdx.x * 256 + threadIdx.x;
    if (p >= LBF) return;
    int pi = p / 48, pj = p % 48;
    float s = 0.f;
#pragma unroll
    for (int u = 0; u < 3; u++)
#pragma unroll
        for (int v = 0; v < 3; v++) {
            int y = pi - 1 + u, x = pj - 1 + v;
            if ((unsigned)y < 48u && (unsigned)x < 48u)
                s += mask[(8 * y) * 384 + 8 * x];
        }
    mm[p] = (s == 0.f) ? 1.f : 0.f;
}

// ---------------- scan: exclusive prefix of mm -> pos[], kinfo ----------------
// kinfo[0]=Kc (survivors), kinfo[1]=Kc padded to 64, kinfo[2]=K1 (static)
__global__ void scan_mm(const float* __restrict__ mmv, int* __restrict__ pos,
                        int* __restrict__ kinfo) {
    int tid = threadIdx.x;
    int loc[9]; int s = 0;
#pragma unroll
    for (int t = 0; t < 9; t++) {
        int m = (mmv[tid * 9 + t] != 0.f);
        loc[t] = s; s += m;
    }
    __shared__ int sh[256];
    sh[tid] = s; __syncthreads();
    for (int off = 1; off < 256; off <<= 1) {
        int v = (tid >= off) ? sh[tid - off] : 0;
        __syncthreads();
        sh[tid] += v;
        __syncthreads();
    }
    int excl = sh[tid] - s;
#pragma unroll
    for (int t = 0; t < 9; t++) pos[tid * 9 + t] = excl + loc[t];
    if (tid == 255) {
        int Kc = excl + s;
        kinfo[0] = Kc;
        kinfo[1] = (Kc + 63) & ~63;
        kinfo[2] = K1;
    }
}

// ---------------- prep: compacted Wt ------------------------------------------
__global__ void prep_wtc(const float* __restrict__ bsrc, const float* __restrict__ mmv,
                         const int* __restrict__ pos, _Float16* __restrict__ wtc) {
    int p = blockIdx.x * 256 + threadIdx.x;   // [0,2304)
    int n = blockIdx.y;                       // [0,2048)
    int b = blockIdx.z;
    if (mmv[p] == 0.f) return;
    int c = n >> 4, u = (n >> 2) & 3, v = n & 3;
    int pi = p / 48, pj = p % 48;
    int y = 2 * pi - 1 + u, x = 2 * pj - 1 + v;
    float val = 0.f;
    if ((unsigned)y < 96u && (unsigned)x < 96u)
        val = bsrc[(((long)b * 128 + c) * 96 + y) * 96 + x];
    wtc[((long)b * 2048 + n) * LDK2 + pos[p]] = (_Float16)val;
}

// ---------------- zero the pad columns [Kc, Kpad) ------------------------------
__global__ void pad_zero(_Float16* __restrict__ buf, const int* __restrict__ kinfo) {
    int row = blockIdx.x;                  // flattened (batch*rows)
    int col = kinfo[0] + threadIdx.x;
    if (col < kinfo[1]) buf[(long)row * LDK2 + col] = (_Float16)0.f;
}

// ---------------- NT GEMM, BK=64: C[M,N] = A[M,K] * B[N,K]^T ------------------
// global_load_lds(16B) staging into unpadded 128B rows; chunk XOR-swizzle
// (phys = logical ^ (row&7)) keeps ds_read_b128 conflict-free. K bound read
// from device (dynamic, mask-compacted for GEMM2).
__global__ __launch_bounds__(256)
void gemm_nt64(const _Float16* __restrict__ A, const _Float16* __restrict__ B,
               float* __restrict__ C, int M, int N, int ldk,
               const int* __restrict__ Kptr, long sA, long sB, long sC) {
    A += blockIdx.z * sA; B += blockIdx.z * sB; C += blockIdx.z * sC;
    const int K = Kptr[0];
    const int tid = threadIdx.x;
    const int lane = tid & 63, wave = tid >> 6;
    const int wr = wave >> 1, wc = wave & 1;
    const int m0 = blockIdx.y * 128, n0 = blockIdx.x * 128;

    __shared__ _Float16 lA[128 * 64];   // 128 rows x 128 B, no pad
    __shared__ _Float16 lB[128 * 64];

    floatx4 acc[4][4] = {};

    const int lm = lane & 15, q = lane >> 4;
    const int pcp = (q ^ (lm & 7)) * 8;      // substep-0 phys offset (halves)

    // staging: wave w call c covers rows (w*4+c)*8 .. +8 (1 KB, lane-linear).
    // lane l -> row +l/8, phys chunk l&7 which holds logical chunk (l&7)^(l>>3)
    const int srow8 = lane >> 3;
    const int gc = ((lane & 7) ^ srow8) * 8;  // global halves offset
    const _Float16* gA[4]; const _Float16* gB[4];
    _Float16* dA[4]; _Float16* dB[4];
#pragma unroll
    for (int c = 0; c < 4; c++) {
        int r = (wave * 4 + c) * 8 + srow8;
        gA[c] = A + (long)(m0 + r) * ldk + gc;
        gB[c] = B + (long)(n0 + r) * ldk + gc;
        dA[c] = &lA[(wave * 4 + c) * 512];
        dB[c] = &lB[(wave * 4 + c) * 512];
    }

    for (int k0 = 0; k0 < K; k0 += 64) {
        __syncthreads();
#pragma unroll
        for (int c = 0; c < 4; c++) gll16(gA[c] + k0, dA[c]);
#pragma unroll
        for (int c = 0; c < 4; c++) gll16(gB[c] + k0, dB[c]);
        __syncthreads();
        half8 af[4], bf[4];
#pragma unroll
        for (int t = 0; t < 4; t++) {
            af[t] = *(const half8*)&lA[(wr * 64 + t * 16 + lm) * 64 + pcp];
            bf[t] = *(const half8*)&lB[(wc * 64 + t * 16 + lm) * 64 + pcp];
        }
#pragma unroll
        for (int i = 0; i < 4; i++)
#pragma unroll
            for (int j = 0; j < 4; j++)
                acc[i][j] = __builtin_amdgcn_mfma_f32_16x16x32_f16(af[i], bf[j], acc[i][j], 0, 0, 0);
#pragma unroll
        for (int t = 0; t < 4; t++) {
            af[t] = *(const half8*)&lA[(wr * 64 + t * 16 + lm) * 64 + (pcp ^ 32)];
            bf[t] = *(const half8*)&lB[(wc * 64 + t * 16 + lm) * 64 + (pcp ^ 32)];
        }
#pragma unroll
        for (int i = 0; i < 4; i++)
#pragma unroll
            for (int j = 0; j < 4; j++)
                acc[i][j] = __builtin_amdgcn_mfma_f32_16x16x32_f16(af[i], bf[j], acc[i][j], 0, 0, 0);
    }
    // C/D layout: col = lane&15, row = (lane>>4)*4 + reg   [m89-verified]
    const int col = n0 + wc * 64 + lm;
    const int rowq = q * 4;
#pragma unroll
    for (int i = 0; i < 4; i++) {
        int row = m0 + wr * 64 + i * 16 + rowq;
#pragma unroll
        for (int j = 0; j < 4; j++)
#pragma unroll
            for (int r = 0; r < 4; r++)
                C[(long)(row + r) * N + col + j * 16] = acc[i][j][r];
    }
}

// ---------------- fused: 9-tap double-diag stencil + masked softmax -----------
// Per block: one foreground row j, batch b. Gathers taps straight from ST
// (skipping masked columns), softmaxes over the 2304 background positions
// (masked entries contribute exp(0-mx)), writes compacted fp16 attTc row.
__global__ __launch_bounds__(256)
void fuse_softmax(const float* __restrict__ ST, const float* __restrict__ mmv,
                  const int* __restrict__ pos, _Float16* __restrict__ attTc) {
    int j = blockIdx.x, b = blockIdx.y;
    const float* S = ST + (long)b * LBF * LBF;
    _Float16* out = attTc + ((long)b * LBF + j) * LDK2;
    int tid = threadIdx.x;
    int Pj = Pswap(j);
    float v[9], msk[9];
    float mx = -1e30f;
#pragma unroll
    for (int u = 0; u < 9; u++) {
        int i = tid + u * 256;
        float mi = mmv[i];
        float x = 0.f;
        if (mi != 0.f) {
            float acc = 0.f;
            int Pi = Pswap(i);
#pragma unroll
            for (int d2 = -1; d2 <= 1; d2++) {
                int i2 = Pi + d2, j2 = Pj + d2;
                if ((unsigned)i2 >= 2304u || (unsigned)j2 >= 2304u) continue;
                int ci = Pswap(i2), rj = Pswap(j2);
#pragma unroll
                for (int d1 = -1; d1 <= 1; d1++) {
                    int cc = ci + d1, rr = rj + d1;
                    if ((unsigned)cc >= 2304u || (unsigned)rr >= 2304u) continue;
                    acc += S[(long)rr * LBF + cc];
                }
            }
            x = acc * 10.f;
        }
        v[u] = x; msk[u] = mi;
        mx = fmaxf(mx, x);
    }
    for (int m = 32; m; m >>= 1) mx = fmaxf(mx, __shfl_xor(mx, m));
    __shared__ float sh[4], sh2[4];
    if ((tid & 63) == 0) sh[tid >> 6] = mx;
    __syncthreads();
    mx = fmaxf(fmaxf(sh[0], sh[1]), fmaxf(sh[2], sh[3]));
    float sum = 0.f;
#pragma unroll
    for (int u = 0; u < 9; u++) { v[u] = __expf(v[u] - mx); sum += v[u]; }
    for (int m = 32; m; m >>= 1) sum += __shfl_xor(sum, m);
    if ((tid & 63) == 0) sh2[tid >> 6] = sum;
    __syncthreads();
    sum = sh2[0] + sh2[1] + sh2[2] + sh2[3];
    float inv = 1.f / sum;
#pragma unroll
    for (int u = 0; u < 9; u++) {
        if (msk[u] != 0.f) out[pos[tid + u * 256]] = (_Float16)(v[u] * inv);
    }
}

// ---------------- scatter: transposed-conv gather, /4 -------------------------
__global__ void scatter_out(const float* __restrict__ Mb_, float* __restrict__ out) {
    int yx = blockIdx.x * 256 + threadIdx.x;  // [0, 9216)
    int c = blockIdx.y, b = blockIdx.z;
    int y = yx / 96, x = yx % 96;
    const float* Mb = Mb_ + (long)b * LBF * 2048;
    float s = 0.f;
    for (int uu = (y + 1) & 1; uu < 4; uu += 2) {
        int fi = (y + 1 - uu) >> 1;
        if ((unsigned)fi >= 48u) continue;
        for (int vv = (x + 1) & 1; vv < 4; vv += 2) {
            int fj = (x + 1 - vv) >> 1;
            if ((unsigned)fj >= 48u) continue;
            s += Mb[(long)(fi * 48 + fj) * 2048 + c * 16 + uu * 4 + vv];
        }
    }
    out[(((long)b * 128 + c) * 96 + y) * 96 + x] = 0.25f * s;
}

extern "C" void kernel_launch(void* const* d_in, const int* in_sizes, int n_in,
                              void* d_out, int out_size, void* d_ws, size_t ws_size,
                              hipStream_t stream) {
    const float* f    = (const float*)d_in[0];
    const float* bsrc = (const float*)d_in[1];
    const float* mask = (const float*)d_in[2];
    float* out = (float*)d_out;

    // workspace regions (reuse):
    //  R0 [0, 85MB):        ST  -> Mout
    //  R1 [85, 127.4MB):    fp+wn -> attTc
    //  R2 [127.4, 165.2MB): Wtc
    //  R3 tail:             mmv, pos, kinfo
    char* ws = (char*)d_ws;
    const size_t offR1   = 84934656;                 // ST: 4*2304*2304*4
    const size_t offWn   = offR1 + 21233664;         // fp: 4*2304*1152*2
    const size_t offWtc  = offR1 + 42467328;
    const size_t offMm   = offWtc + (size_t)4 * 2048 * LDK2 * 2;  // +37748736
    const size_t offPos  = offMm + 9216;
    const size_t offKin  = offPos + 9216;
    const size_t NEED    = offKin + 64;
    if (ws_size < NEED) return;  // visible failure, no OOB writes

    float*    ST    = (float*)(ws + 0);
    float*    Mout  = (float*)(ws + 0);
    _Float16* fp    = (_Float16*)(ws + offR1);
    _Float16* wn    = (_Float16*)(ws + offWn);
    _Float16* attTc = (_Float16*)(ws + offR1);
    _Float16* Wtc   = (_Float16*)(ws + offWtc);
    float*    mmv   = (float*)(ws + offMm);
    int*      pos   = (int*)(ws + offPos);
    int*      kinfo = (int*)(ws + offKin);

    prep_mm<<<dim3(9), 256, 0, stream>>>(mask, mmv);
    scan_mm<<<dim3(1), 256, 0, stream>>>(mmv, pos, kinfo);
    prep_fp<<<dim3(9, 2304, 4), 128, 0, stream>>>(f, fp);
    prep_wn<<<dim3(2304, 4), 128, 0, stream>>>(bsrc, wn);
    prep_wtc<<<dim3(9, 2048, 4), 256, 0, stream>>>(bsrc, mmv, pos, Wtc);
    pad_zero<<<dim3(4 * 2048), 64, 0, stream>>>(Wtc, kinfo);

    // GEMM1: ST[j,i] = sum_k fp[j,k] * wn[i,k]
    gemm_nt64<<<dim3(18, 18, 4), 256, 0, stream>>>(fp, wn, ST, 2304, 2304, K1,
        kinfo + 2, (long)2304 * K1, (long)2304 * K1, (long)2304 * 2304);

    pad_zero<<<dim3(4 * 2304), 64, 0, stream>>>(attTc, kinfo);  // after GEMM1 (region reuse)
    fuse_softmax<<<dim3(2304, 4), 256, 0, stream>>>(ST, mmv, pos, attTc);

    // GEMM2 (compacted K): M[j,n] = sum_kc attTc[j,kc] * Wtc[n,kc]
    gemm_nt64<<<dim3(16, 18, 4), 256, 0, stream>>>(attTc, Wtc, Mout, 2304, 2048, LDK2,
        kinfo + 1, (long)2304 * LDK2, (long)2048 * LDK2, (long)2304 * 2048);

    scatter_out<<<dim3(36, 128, 4), 256, 0, stream>>>(Mout, out);
}